// Round 1
// baseline (1032.483 us; speedup 1.0000x reference)
//
#include <hip/hip_runtime.h>

// Problem constants (from reference): B=1, C=32, H2=256, W2=480, D=32.
// Output: (1, 64, 32, 256, 480) fp32.
//   out[c2, d, h, w] = imgl[c2, h, w]                    for c2 < 32
//   out[c2, d, h, w] = (w >= d) ? imgr[c2-32, h, w-d] : 0 for c2 >= 32
constexpr int C   = 32;
constexpr int H2  = 256;
constexpr int W2  = 480;
constexpr int DSP = 32;
constexpr int W4  = W2 / 4;                 // 120 float4 per row
constexpr int TOTAL4 = 64 * DSP * H2 * W4;  // 62,914,560 float4 stores

// Each (c2, d) plane is H2*W4 = 30720 float4 = exactly 120 blocks of 256
// threads, so c2/d (and hence the left/right branch) are block-uniform.
__global__ __launch_bounds__(256) void costvol_kernel(
    const float* __restrict__ imgl,
    const float* __restrict__ imgr,
    float4* __restrict__ out)
{
    unsigned idx = blockIdx.x * 256u + threadIdx.x;
    if (idx >= (unsigned)TOTAL4) return;

    unsigned w4 = idx % W4;
    unsigned t  = idx / W4;          // t = ((c2*DSP + d)*H2 + h)
    unsigned h  = t % H2;
    unsigned t2 = t / H2;            // t2 = c2*DSP + d
    unsigned d  = t2 & (DSP - 1);
    unsigned c2 = t2 >> 5;

    float4 v;
    if (c2 < (unsigned)C) {
        // left half: broadcast imgl across d — aligned float4 copy
        v = reinterpret_cast<const float4*>(imgl)[(c2 * H2 + h) * W4 + w4];
    } else {
        // right half: shift by d, zero-fill w < d. Scalar reads (shift
        // breaks 16B alignment); served from L1/L2/L3 — imgr is 15.7 MB.
        unsigned c    = c2 - C;
        unsigned base = (c * H2 + h) * W2;
        int w = (int)(w4 * 4) - (int)d;   // source index for lane's first elem
        v.x = (w + 0 >= 0) ? imgr[base + w + 0] : 0.0f;
        v.y = (w + 1 >= 0) ? imgr[base + w + 1] : 0.0f;
        v.z = (w + 2 >= 0) ? imgr[base + w + 2] : 0.0f;
        v.w = (w + 3 >= 0) ? imgr[base + w + 3] : 0.0f;
    }
    out[idx] = v;
}

extern "C" void kernel_launch(void* const* d_in, const int* in_sizes, int n_in,
                              void* d_out, int out_size, void* d_ws, size_t ws_size,
                              hipStream_t stream) {
    const float* imgl = (const float*)d_in[0];
    const float* imgr = (const float*)d_in[1];
    float4* out = (float4*)d_out;

    constexpr int threads = 256;
    constexpr int blocks  = TOTAL4 / threads;  // 245,760 — exact
    costvol_kernel<<<blocks, threads, 0, stream>>>(imgl, imgr, out);
}